// Round 8
// baseline (411.376 us; speedup 1.0000x reference)
//
#include <hip/hip_runtime.h>
#include <cmath>
#include <cstdint>

#define NBATCH 16
#define HH 56
#define WW 56
#define CCH 256
#define NHEADS 8
#define HDIM 32
#define WSP 7
#define NWIN 128
#define LTOK 392
#define NTOK 3136

#define KB_STRIDE 12800     // 400 rows x 32 ch (bf16)
#define VT_ROW 424          // padded keys per channel row
#define VT_STRIDE 14336     // 32 x 448 elems per wh (28,672 B = 7 x 4096)
#define PB_S 36

typedef __attribute__((ext_vector_type(8))) __bf16 bf16x8;
typedef __attribute__((ext_vector_type(4))) __bf16 bf16x4;
typedef __attribute__((ext_vector_type(4))) float f32x4;

static __device__ __forceinline__ uint32_t pkbf(float a, float b) {
    __bf16 x = (__bf16)a, y = (__bf16)b;
    uint16_t xu = __builtin_bit_cast(uint16_t, x);
    uint16_t yu = __builtin_bit_cast(uint16_t, y);
    return (uint32_t)xu | ((uint32_t)yu << 16);
}

// ---------------------------------------------------------------- pack K/V/W
// One block per (win, head). K -> Kb[wh][400][32] bf16 (rows>=392 zero).
// V -> Vt[wh][32][424] bf16 transposed (keys>=392 zero) via LDS f32 transpose.
// Also distributes the 9*256*256 W transpose across the 1024 blocks.
__global__ __launch_bounds__(256) void pack_kvw(const float* __restrict__ qkv,
        const float* __restrict__ wconv, __bf16* __restrict__ Kb,
        __bf16* __restrict__ Vt, __bf16* __restrict__ Wt) {
    const int wh = blockIdx.x;
    const int win = wh >> 3, h = wh & 7;
    const int b = win >> 3, wi = win & 7;
    const int tid = threadIdx.x;
    __shared__ float vt_s[32 * 428];    // 54,784 B; stride 428: banks ok, 16B-aligned rows

    const size_t plane = (size_t)NBATCH * NTOK * CCH;
    const float* ksrc = qkv + plane + ((size_t)b * NTOK) * CCH + h * HDIM;
    const float* vsrc = qkv + 2 * plane + ((size_t)b * NTOK) * CCH + h * HDIM;

    // ---- W slice: 576 items/block
#pragma unroll
    for (int i = 0; i < 3; i++) {
        int j = i * 256 + tid;
        if (j < 576) {
            int idx = wh * 576 + j;
            int tap = idx / (CCH * CCH);
            int rem = idx % (CCH * CCH);
            int co = rem / CCH, ci = rem % CCH;
            Wt[idx] = (__bf16)(wconv[(size_t)tap * CCH * CCH + (size_t)ci * CCH + co]);
        }
    }
    // ---- K: 400 rows x 4 ch-groups
#pragma unroll
    for (int it = 0; it < 7; it++) {
        int idx = it * 256 + tid;
        if (idx < 1600) {
            int row = idx >> 2, chg = idx & 3;
            bf16x8 val;
            if (row < LTOK) {
                int tok = (row / 7) * WW + wi * WSP + row % 7;
                const float* p = ksrc + (size_t)tok * CCH + chg * 8;
                f32x4 a = *(const f32x4*)p;
                f32x4 c = *(const f32x4*)(p + 4);
#pragma unroll
                for (int i = 0; i < 4; i++) { val[i] = (__bf16)a[i]; val[4 + i] = (__bf16)c[i]; }
            } else {
#pragma unroll
                for (int i = 0; i < 8; i++) val[i] = (__bf16)0.0f;
            }
            *(bf16x8*)&Kb[(size_t)wh * KB_STRIDE + row * 32 + chg * 8] = val;
        }
    }
    // ---- V into LDS transposed: vt_s[ch][key]
#pragma unroll
    for (int it = 0; it < 8; it++) {
        int chg = it >> 1;
        int key = (it & 1) * 256 + tid;
        if (key < LTOK) {
            int tok = (key / 7) * WW + wi * WSP + key % 7;
            const float* p = vsrc + (size_t)tok * CCH + chg * 8;
            f32x4 a = *(const f32x4*)p;
            f32x4 c = *(const f32x4*)(p + 4);
#pragma unroll
            for (int i = 0; i < 4; i++) {
                vt_s[(chg * 8 + i) * 428 + key] = a[i];
                vt_s[(chg * 8 + 4 + i) * 428 + key] = c[i];
            }
        }
    }
    __syncthreads();
    // ---- transposed read -> bf16, coalesced global write (kg-major lanes)
#pragma unroll
    for (int it = 0; it < 7; it++) {
        int idx = it * 256 + tid;
        if (idx < 32 * 53) {
            int d = idx / 53, kg = idx % 53;
            bf16x8 o;
            if (kg < 49) {                       // keys 0..391 valid (49*8=392)
                const float* s = &vt_s[d * 428 + kg * 8];
#pragma unroll
                for (int i = 0; i < 8; i++) o[i] = (__bf16)s[i];
            } else {
#pragma unroll
                for (int i = 0; i < 8; i++) o[i] = (__bf16)0.0f;
            }
            *(bf16x8*)&Vt[(size_t)wh * VT_STRIDE + d * VT_ROW + kg * 8] = o;
        }
    }
}

// ---------------------------------------------------------------- LePE conv
// Implicit GEMM. Block = (window, 8-row stripe): M=56 pos (padded 64), N=256.
// A: halo rows in LDS [10][9][264]. B: per-wave async global_load_lds pipeline,
// double-buffered per-wave 4KB LDS slots, counted vmcnt(4), no K-loop barriers.
#define AV_R 10
#define AV_C 9
#define AV_S 264
__global__ __launch_bounds__(256, 2) void lepe_conv(const float* __restrict__ qkv,
        const __bf16* __restrict__ Wt, const float* __restrict__ bconv,
        float* __restrict__ out) {
    const int bid = blockIdx.x;
    const int win = bid / 7, rb = bid % 7;
    const int b = win >> 3, wi = win & 7;
    const int rbase = rb * 8;
    const int tid = threadIdx.x;
    const int lane = tid & 63, wv = tid >> 6;
    const int lr = lane & 15, lg = lane >> 4;
    __shared__ __bf16 Av[AV_R * AV_C * AV_S];   // 47,520 B
    __shared__ __bf16 Bs[2][4][2048];           // 32,768 B
    const float* vsrc = qkv + 2 * (size_t)NBATCH * NTOK * CCH;

    for (int t = tid; t < AV_R * AV_C * 64; t += 256) {
        int rr = t / (AV_C * 64);
        int rem = t % (AV_C * 64);
        int cc = rem / 64, chg = rem % 64;
        int ar = rbase + rr - 1, c = cc - 1;
        f32x4 v = {0.f, 0.f, 0.f, 0.f};
        if (ar >= 0 && ar < HH && c >= 0 && c < WSP) {
            int token = ar * WW + wi * WSP + c;
            v = *(const f32x4*)(vsrc + ((size_t)b * NTOK + token) * CCH + chg * 4);
        }
        bf16x4 w;
#pragma unroll
        for (int i = 0; i < 4; i++) w[i] = (__bf16)v[i];
        *(bf16x4*)&Av[(rr * AV_C + cc) * AV_S + chg * 4] = w;
    }
    __syncthreads();

    f32x4 acc[4][4];
#pragma unroll
    for (int i = 0; i < 4; i++)
#pragma unroll
        for (int j = 0; j < 4; j++) acc[i][j] = (f32x4){0.f, 0.f, 0.f, 0.f};

    int ab[4];
#pragma unroll
    for (int mt = 0; mt < 4; mt++) {
        int p = mt * 16 + lr; if (p > 55) p = 55;
        ab[mt] = ((p / 7) * AV_C + (p % 7)) * AV_S + lg * 8;
    }
    int bro[4];
#pragma unroll
    for (int nt = 0; nt < 4; nt++)
        bro[nt] = (nt * 16 + lr) * 32 + ((lg ^ ((lr >> 1) & 3)) * 8);
    const __bf16* wsrc = Wt + (size_t)(wv * 64 + (lane >> 2)) * CCH
                            + (((lane & 3) ^ ((lane >> 3) & 3)) * 8);
    __bf16* b0 = &Bs[0][wv][0];
    __bf16* b1 = &Bs[1][wv][0];

#define GLDS(gp, lp)                                                        \
    __builtin_amdgcn_global_load_lds(                                       \
        (const __attribute__((address_space(1))) void*)(gp),                \
        (__attribute__((address_space(3))) void*)(lp), 16, 0, 0)
#define ISSUE(s, lb) do {                                                   \
        const int tp_ = (s) >> 3, kq_ = (s) & 7;                            \
        const __bf16* g_ = wsrc + tp_ * (CCH * CCH) + kq_ * 32;             \
        GLDS(g_, lb);                                                       \
        GLDS(g_ + 16 * CCH, (lb) + 512);                                    \
        GLDS(g_ + 32 * CCH, (lb) + 1024);                                   \
        GLDS(g_ + 48 * CCH, (lb) + 1536);                                   \
    } while (0)
#define STEPX(s, lb, doiss, s2) do {                                        \
        const int tap_ = (s) >> 3, ks_ = (s) & 7;                           \
        const int dy_ = (tap_ >= 6) ? 2 : ((tap_ >= 3) ? 1 : 0);            \
        const int offa = (tap_ + 6 * dy_) * AV_S + ks_ * 32;                \
        bf16x8 a_[4], bb_[4];                                               \
        _Pragma("unroll")                                                   \
        for (int mt = 0; mt < 4; mt++)                                      \
            a_[mt] = *(const bf16x8*)&Av[ab[mt] + offa];                    \
        _Pragma("unroll")                                                   \
        for (int nt = 0; nt < 4; nt++)                                      \
            bb_[nt] = *(const bf16x8*)&(lb)[bro[nt]];                       \
        asm volatile("s_waitcnt lgkmcnt(0)" ::: "memory");                  \
        __builtin_amdgcn_sched_barrier(0);                                  \
        if (doiss) ISSUE(s2, lb);                                           \
        _Pragma("unroll")                                                   \
        for (int mt = 0; mt < 4; mt++)                                      \
            _Pragma("unroll")                                               \
            for (int nt = 0; nt < 4; nt++)                                  \
                acc[mt][nt] = __builtin_amdgcn_mfma_f32_16x16x32_bf16(      \
                    a_[mt], bb_[nt], acc[mt][nt], 0, 0, 0);                 \
    } while (0)
#define WAIT4 asm volatile("s_waitcnt vmcnt(4)" ::: "memory")
#define WAIT0 asm volatile("s_waitcnt vmcnt(0)" ::: "memory")

    ISSUE(0, b0);
    ISSUE(1, b1);
    for (int s = 0; s < 70; s += 2) {
        WAIT4; STEPX(s, b0, 1, s + 2);
        WAIT4; STEPX(s + 1, b1, 1, s + 3);
    }
    WAIT4; STEPX(70, b0, 0, 0);
    WAIT0; STEPX(71, b1, 0, 0);
#undef ISSUE
#undef STEPX
#undef WAIT4
#undef WAIT0

#pragma unroll
    for (int nt = 0; nt < 4; nt++) {
        int ch = wv * 64 + nt * 16 + lr;
        float bias = bconv[ch];
#pragma unroll
        for (int mt = 0; mt < 4; mt++) {
#pragma unroll
            for (int r = 0; r < 4; r++) {
                int p = mt * 16 + lg * 4 + r;
                if (p < 56) {
                    int ar = rbase + p / 7, c = p % 7;
                    int token = ar * WW + wi * WSP + c;
                    out[((size_t)b * NTOK + token) * CCH + ch] = acc[mt][nt][r] + bias;
                }
            }
        }
    }
}

// ---------------------------------------------------------------- attention
// One block per (win, head), 256 threads (4 waves), 4 blocks/CU.
// Vs (V^T bf16) staged via 7 exact global_load_lds iterations from Vt.
// K fragments read DIRECTLY from global bf16 Kb (L2-resident, coalesced).
// Swapped QK^T (lane owns q-row), two macro-expanded key halves, online
// rescale; P transposed via per-wave LDS bounce. VGPR cap 128 via (256,4).
__global__ __launch_bounds__(256, 4) void attn3(const float* __restrict__ qkv,
        const __bf16* __restrict__ Kb, const __bf16* __restrict__ Vt,
        float* __restrict__ out) {
    const int wh = blockIdx.x;
    const int win = wh >> 3, h = wh & 7;
    const int b = win >> 3, wi = win & 7;
    const int tid = threadIdx.x;
    const int lane = tid & 63, wv = tid >> 6;
    const int lr = lane & 15, lg = lane >> 4;
    const float scale = 0.17677669529663687f;   // 32^-0.5

    __shared__ __bf16 Vs[VT_STRIDE];            // 28,672 B ([32][424] used)
    __shared__ __bf16 Pb[4][16 * PB_S];         //  4,608 B  (total 33,280)

    const size_t plane = (size_t)NBATCH * NTOK * CCH;
    const float* qsrc = qkv + ((size_t)b * NTOK) * CCH + h * HDIM;
    const __bf16* kb = Kb + (size_t)wh * KB_STRIDE;
    const __bf16* vt = Vt + (size_t)wh * VT_STRIDE;

    // ---- stage Vs: 7 x (256 lanes x 16 B) = 28,672 B, linear copy
#pragma unroll
    for (int i = 0; i < 7; i++) {
        GLDS(vt + (i * 256 + tid) * 8, &Vs[(i * 256 + wv * 64) * 8]);
    }
    asm volatile("s_waitcnt vmcnt(0)" ::: "memory");
    __syncthreads();
#undef GLDS

    __bf16* pb = Pb[wv];
    for (int tile = wv; tile < 25; tile += 4) {
        // ---- Q fragment (B-operand) direct from f32, scaled
        int qrow = tile * 16 + lr;
        int qe = qrow < LTOK ? qrow : LTOK - 1;
        int tokq = (qe / 7) * WW + wi * WSP + qe % 7;
        const float* qp = qsrc + (size_t)tokq * CCH + lg * 8;
        f32x4 qa = *(const f32x4*)qp;
        f32x4 qc = *(const f32x4*)(qp + 4);
        bf16x8 aq;
#pragma unroll
        for (int i = 0; i < 4; i++) {
            aq[i] = (__bf16)(qa[i] * scale);
            aq[4 + i] = (__bf16)(qc[i] * scale);
        }

        float m_run = 0.f, sum_run = 0.f;
        f32x4 xacc[2] = {{0.f, 0.f, 0.f, 0.f}, {0.f, 0.f, 0.f, 0.f}};

#define HALF_PASS(NT, TB, NC, FIRST) do {                                   \
    f32x4 s[NT];                                                            \
    _Pragma("unroll")                                                       \
    for (int t = 0; t < NT; t++) {                                          \
        bf16x8 bk = *(const bf16x8*)(kb + ((TB + t) * 16 + lr) * 32 + lg * 8); \
        s[t] = __builtin_amdgcn_mfma_f32_16x16x32_bf16(                     \
            bk, aq, (f32x4){0.f, 0.f, 0.f, 0.f}, 0, 0, 0);                  \
    }                                                                       \
    f32x4 vm = s[0];                                                        \
    _Pragma("unroll")                                                       \
    for (int t = 1; t < 12; t++) {                                          \
        _Pragma("unroll")                                                   \
        for (int r = 0; r < 4; r++) vm[r] = fmaxf(vm[r], s[t][r]);          \
    }                                                                       \
    if (NT == 13 && lg < 2) {                                               \
        _Pragma("unroll")                                                   \
        for (int r = 0; r < 4; r++) vm[r] = fmaxf(vm[r], s[NT - 1][r]);     \
    }                                                                       \
    float mh = fmaxf(fmaxf(vm[0], vm[1]), fmaxf(vm[2], vm[3]));             \
    mh = fmaxf(mh, __shfl_xor(mh, 16, 64));                                 \
    mh = fmaxf(mh, __shfl_xor(mh, 32, 64));                                 \
    float m_new = FIRST ? mh : fmaxf(m_run, mh);                            \
    if (!FIRST) {                                                           \
        float f = __expf(m_run - m_new);                                    \
        sum_run *= f;                                                       \
        _Pragma("unroll")                                                   \
        for (int r = 0; r < 4; r++) {                                       \
            float fr = __shfl(f, 4 * lg + r, 64);                           \
            xacc[0][r] *= fr;                                               \
            xacc[1][r] *= fr;                                               \
        }                                                                   \
    }                                                                       \
    m_run = m_new;                                                          \
    f32x4 vsum = {0.f, 0.f, 0.f, 0.f};                                      \
    _Pragma("unroll")                                                       \
    for (int t = 0; t < 12; t++) {                                          \
        _Pragma("unroll")                                                   \
        for (int r = 0; r < 4; r++) {                                       \
            float e = __expf(s[t][r] - m_new);                              \
            s[t][r] = e;                                                    \
            vsum[r] += e;                                                   \
        }                                                                   \
    }                                                                       \
    if (NT == 13) {                                                         \
        if (lg < 2) {                                                       \
            _Pragma("unroll")                                               \
            for (int r = 0; r < 4; r++) {                                   \
                float e = __expf(s[NT - 1][r] - m_new);                     \
                s[NT - 1][r] = e;                                           \
                vsum[r] += e;                                               \
            }                                                               \
        } else {                                                            \
            _Pragma("unroll")                                               \
            for (int r = 0; r < 4; r++) s[NT - 1][r] = 0.f;                 \
        }                                                                   \
    }                                                                       \
    float sumh = (vsum[0] + vsum[1]) + (vsum[2] + vsum[3]);                 \
    sumh += __shfl_xor(sumh, 16, 64);                                       \
    sumh += __shfl_xor(sumh, 32, 64);                                       \
    sum_run += sumh;                                                        \
    _Pragma("unroll")                                                       \
    for (int c = 0; c < NC; c++) {                                          \
        uint2 wa, wb;                                                       \
        wa.x = pkbf(s[2 * c][0], s[2 * c][1]);                              \
        wa.y = pkbf(s[2 * c][2], s[2 * c][3]);                              \
        if (2 * c + 1 < NT) {                                               \
            wb.x = pkbf(s[2 * c + 1][0], s[2 * c + 1][1]);                  \
            wb.y = pkbf(s[2 * c + 1][2], s[2 * c + 1][3]);                  \
        } else {                                                            \
            wb.x = 0u; wb.y = 0u;                                           \
        }                                                                   \
        *(uint2*)&pb[lr * PB_S + 4 * lg] = wa;                              \
        *(uint2*)&pb[lr * PB_S + 16 + 4 * lg] = wb;                         \
        bf16x4 lo = *(const bf16x4*)&pb[lr * PB_S + 8 * lg];                \
        bf16x4 hi = *(const bf16x4*)&pb[lr * PB_S + 8 * lg + 4];            \
        bf16x8 ap;                                                          \
        _Pragma("unroll")                                                   \
        for (int i = 0; i < 4; i++) { ap[i] = lo[i]; ap[4 + i] = hi[i]; }   \
        const int kbase = TB * 16 + c * 32;                                 \
        _Pragma("unroll")                                                   \
        for (int nt = 0; nt < 2; nt++) {                                    \
            bf16x8 bv = *(const bf16x8*)&Vs[(nt * 16 + lr) * VT_ROW + kbase + lg * 8]; \
            xacc[nt] = __builtin_amdgcn_mfma_f32_16x16x32_bf16(             \
                ap, bv, xacc[nt], 0, 0, 0);                                 \
        }                                                                   \
    }                                                                       \
} while (0)

        HALF_PASS(12, 0, 6, 1);
        HALF_PASS(13, 12, 7, 0);
#undef HALF_PASS

        // ---- write out (RMW add onto conv output); rows q = tile*16+4lg+r
        float inv = 1.0f / sum_run;
#pragma unroll
        for (int r = 0; r < 4; r++) {
            float invr = __shfl(inv, 4 * lg + r, 64);
            int q = tile * 16 + 4 * lg + r;
            if (q < LTOK) {
                int rI = q / 7, c = q % 7;
                size_t base = ((size_t)b * NTOK + rI * WW + wi * WSP + c) * CCH + h * HDIM;
#pragma unroll
                for (int nt = 0; nt < 2; nt++)
                    out[base + nt * 16 + lr] += xacc[nt][r] * invr;
            }
        }
    }
}

// ---------------------------------------------------------------- launch
extern "C" void kernel_launch(void* const* d_in, const int* in_sizes, int n_in,
                              void* d_out, int out_size, void* d_ws, size_t ws_size,
                              hipStream_t stream) {
    const float* qkv = (const float*)d_in[0];
    const float* wconv = (const float*)d_in[1];
    const float* bconv = (const float*)d_in[2];
    float* out = (float*)d_out;
    char* ws = (char*)d_ws;

    const size_t KB_BYTES = (size_t)NWIN * NHEADS * KB_STRIDE * 2;   // 26,214,400
    const size_t VT_BYTES = (size_t)NWIN * NHEADS * VT_STRIDE * 2;   // 29,360,128
    const size_t WT_BYTES = (size_t)9 * CCH * CCH * 2;               //  1,179,648
    if (ws_size < KB_BYTES + VT_BYTES + WT_BYTES) return;

    __bf16* Kb = (__bf16*)ws;
    __bf16* Vt = (__bf16*)(ws + KB_BYTES);
    __bf16* Wt = (__bf16*)(ws + KB_BYTES + VT_BYTES);

    pack_kvw<<<NWIN * NHEADS, 256, 0, stream>>>(qkv, wconv, Kb, Vt, Wt);
    lepe_conv<<<NWIN * 7, 256, 0, stream>>>(qkv, Wt, bconv, out);
    attn3<<<NWIN * NHEADS, 256, 0, stream>>>(qkv, Kb, Vt, out);
}

// Round 9
// 265.269 us; speedup vs baseline: 1.5508x; 1.5508x over previous
//
#include <hip/hip_runtime.h>
#include <cmath>
#include <cstdint>

#define NBATCH 16
#define HH 56
#define WW 56
#define CCH 256
#define NHEADS 8
#define HDIM 32
#define WSP 7
#define NWIN 128
#define LTOK 392
#define NTOK 3136

#define KB_STRIDE 12800     // 400 rows x 32 ch (bf16)
#define VT_ROW 424          // padded keys per channel row
#define VT_STRIDE 14336     // 32 x 448 elems per wh (28,672 B = 7 x 4096)
#define PB_S 36

typedef __attribute__((ext_vector_type(8))) __bf16 bf16x8;
typedef __attribute__((ext_vector_type(4))) __bf16 bf16x4;
typedef __attribute__((ext_vector_type(4))) float f32x4;

static __device__ __forceinline__ uint32_t pkbf(float a, float b) {
    __bf16 x = (__bf16)a, y = (__bf16)b;
    uint16_t xu = __builtin_bit_cast(uint16_t, x);
    uint16_t yu = __builtin_bit_cast(uint16_t, y);
    return (uint32_t)xu | ((uint32_t)yu << 16);
}

// ---------------------------------------------------------------- pack K/V/W
// One block per (win, head). K -> Kb[wh][400][32] bf16 (rows>=392 zero).
// V -> Vt[wh][32][424] bf16 transposed (keys>=392 zero) via LDS f32 transpose.
// Also distributes the 9*256*256 W transpose across the 1024 blocks.
__global__ __launch_bounds__(256) void pack_kvw(const float* __restrict__ qkv,
        const float* __restrict__ wconv, __bf16* __restrict__ Kb,
        __bf16* __restrict__ Vt, __bf16* __restrict__ Wt) {
    const int wh = blockIdx.x;
    const int win = wh >> 3, h = wh & 7;
    const int b = win >> 3, wi = win & 7;
    const int tid = threadIdx.x;
    __shared__ float vt_s[32 * 428];    // 54,784 B

    const size_t plane = (size_t)NBATCH * NTOK * CCH;
    const float* ksrc = qkv + plane + ((size_t)b * NTOK) * CCH + h * HDIM;
    const float* vsrc = qkv + 2 * plane + ((size_t)b * NTOK) * CCH + h * HDIM;

    // ---- W slice: 576 items/block
#pragma unroll
    for (int i = 0; i < 3; i++) {
        int j = i * 256 + tid;
        if (j < 576) {
            int idx = wh * 576 + j;
            int tap = idx / (CCH * CCH);
            int rem = idx % (CCH * CCH);
            int co = rem / CCH, ci = rem % CCH;
            Wt[idx] = (__bf16)(wconv[(size_t)tap * CCH * CCH + (size_t)ci * CCH + co]);
        }
    }
    // ---- K: 400 rows x 4 ch-groups
#pragma unroll
    for (int it = 0; it < 7; it++) {
        int idx = it * 256 + tid;
        if (idx < 1600) {
            int row = idx >> 2, chg = idx & 3;
            bf16x8 val;
            if (row < LTOK) {
                int tok = (row / 7) * WW + wi * WSP + row % 7;
                const float* p = ksrc + (size_t)tok * CCH + chg * 8;
                f32x4 a = *(const f32x4*)p;
                f32x4 c = *(const f32x4*)(p + 4);
#pragma unroll
                for (int i = 0; i < 4; i++) { val[i] = (__bf16)a[i]; val[4 + i] = (__bf16)c[i]; }
            } else {
#pragma unroll
                for (int i = 0; i < 8; i++) val[i] = (__bf16)0.0f;
            }
            *(bf16x8*)&Kb[(size_t)wh * KB_STRIDE + row * 32 + chg * 8] = val;
        }
    }
    // ---- V into LDS transposed: vt_s[ch][key]
#pragma unroll
    for (int it = 0; it < 8; it++) {
        int chg = it >> 1;
        int key = (it & 1) * 256 + tid;
        if (key < LTOK) {
            int tok = (key / 7) * WW + wi * WSP + key % 7;
            const float* p = vsrc + (size_t)tok * CCH + chg * 8;
            f32x4 a = *(const f32x4*)p;
            f32x4 c = *(const f32x4*)(p + 4);
#pragma unroll
            for (int i = 0; i < 4; i++) {
                vt_s[(chg * 8 + i) * 428 + key] = a[i];
                vt_s[(chg * 8 + 4 + i) * 428 + key] = c[i];
            }
        }
    }
    __syncthreads();
    // ---- transposed read -> bf16, coalesced global write (kg-major lanes)
#pragma unroll
    for (int it = 0; it < 7; it++) {
        int idx = it * 256 + tid;
        if (idx < 32 * 53) {
            int d = idx / 53, kg = idx % 53;
            bf16x8 o;
            if (kg < 49) {                       // keys 0..391 valid (49*8=392)
                const float* s = &vt_s[d * 428 + kg * 8];
#pragma unroll
                for (int i = 0; i < 8; i++) o[i] = (__bf16)s[i];
            } else {
#pragma unroll
                for (int i = 0; i < 8; i++) o[i] = (__bf16)0.0f;
            }
            *(bf16x8*)&Vt[(size_t)wh * VT_STRIDE + d * VT_ROW + kg * 8] = o;
        }
    }
}

// ---------------------------------------------------------------- LePE conv
// Implicit GEMM. Block = (window, 8-row stripe): M=56 pos (padded 64), N=256.
// A: halo rows in LDS [10][9][264]. B: per-wave async global_load_lds pipeline,
// double-buffered per-wave 4KB LDS slots, counted vmcnt(4), no K-loop barriers.
#define AV_R 10
#define AV_C 9
#define AV_S 264
__global__ __launch_bounds__(256, 2) void lepe_conv(const float* __restrict__ qkv,
        const __bf16* __restrict__ Wt, const float* __restrict__ bconv,
        float* __restrict__ out) {
    const int bid = blockIdx.x;
    const int win = bid / 7, rb = bid % 7;
    const int b = win >> 3, wi = win & 7;
    const int rbase = rb * 8;
    const int tid = threadIdx.x;
    const int lane = tid & 63, wv = tid >> 6;
    const int lr = lane & 15, lg = lane >> 4;
    __shared__ __bf16 Av[AV_R * AV_C * AV_S];   // 47,520 B
    __shared__ __bf16 Bs[2][4][2048];           // 32,768 B
    const float* vsrc = qkv + 2 * (size_t)NBATCH * NTOK * CCH;

    for (int t = tid; t < AV_R * AV_C * 64; t += 256) {
        int rr = t / (AV_C * 64);
        int rem = t % (AV_C * 64);
        int cc = rem / 64, chg = rem % 64;
        int ar = rbase + rr - 1, c = cc - 1;
        f32x4 v = {0.f, 0.f, 0.f, 0.f};
        if (ar >= 0 && ar < HH && c >= 0 && c < WSP) {
            int token = ar * WW + wi * WSP + c;
            v = *(const f32x4*)(vsrc + ((size_t)b * NTOK + token) * CCH + chg * 4);
        }
        bf16x4 w;
#pragma unroll
        for (int i = 0; i < 4; i++) w[i] = (__bf16)v[i];
        *(bf16x4*)&Av[(rr * AV_C + cc) * AV_S + chg * 4] = w;
    }
    __syncthreads();

    f32x4 acc[4][4];
#pragma unroll
    for (int i = 0; i < 4; i++)
#pragma unroll
        for (int j = 0; j < 4; j++) acc[i][j] = (f32x4){0.f, 0.f, 0.f, 0.f};

    int ab[4];
#pragma unroll
    for (int mt = 0; mt < 4; mt++) {
        int p = mt * 16 + lr; if (p > 55) p = 55;
        ab[mt] = ((p / 7) * AV_C + (p % 7)) * AV_S + lg * 8;
    }
    int bro[4];
#pragma unroll
    for (int nt = 0; nt < 4; nt++)
        bro[nt] = (nt * 16 + lr) * 32 + ((lg ^ ((lr >> 1) & 3)) * 8);
    const __bf16* wsrc = Wt + (size_t)(wv * 64 + (lane >> 2)) * CCH
                            + (((lane & 3) ^ ((lane >> 3) & 3)) * 8);
    __bf16* b0 = &Bs[0][wv][0];
    __bf16* b1 = &Bs[1][wv][0];

#define GLDS(gp, lp)                                                        \
    __builtin_amdgcn_global_load_lds(                                       \
        (const __attribute__((address_space(1))) void*)(gp),                \
        (__attribute__((address_space(3))) void*)(lp), 16, 0, 0)
#define ISSUE(s, lb) do {                                                   \
        const int tp_ = (s) >> 3, kq_ = (s) & 7;                            \
        const __bf16* g_ = wsrc + tp_ * (CCH * CCH) + kq_ * 32;             \
        GLDS(g_, lb);                                                       \
        GLDS(g_ + 16 * CCH, (lb) + 512);                                    \
        GLDS(g_ + 32 * CCH, (lb) + 1024);                                   \
        GLDS(g_ + 48 * CCH, (lb) + 1536);                                   \
    } while (0)
#define STEPX(s, lb, doiss, s2) do {                                        \
        const int tap_ = (s) >> 3, ks_ = (s) & 7;                           \
        const int dy_ = (tap_ >= 6) ? 2 : ((tap_ >= 3) ? 1 : 0);            \
        const int offa = (tap_ + 6 * dy_) * AV_S + ks_ * 32;                \
        bf16x8 a_[4], bb_[4];                                               \
        _Pragma("unroll")                                                   \
        for (int mt = 0; mt < 4; mt++)                                      \
            a_[mt] = *(const bf16x8*)&Av[ab[mt] + offa];                    \
        _Pragma("unroll")                                                   \
        for (int nt = 0; nt < 4; nt++)                                      \
            bb_[nt] = *(const bf16x8*)&(lb)[bro[nt]];                       \
        asm volatile("s_waitcnt lgkmcnt(0)" ::: "memory");                  \
        __builtin_amdgcn_sched_barrier(0);                                  \
        if (doiss) ISSUE(s2, lb);                                           \
        _Pragma("unroll")                                                   \
        for (int mt = 0; mt < 4; mt++)                                      \
            _Pragma("unroll")                                               \
            for (int nt = 0; nt < 4; nt++)                                  \
                acc[mt][nt] = __builtin_amdgcn_mfma_f32_16x16x32_bf16(      \
                    a_[mt], bb_[nt], acc[mt][nt], 0, 0, 0);                 \
    } while (0)
#define WAIT4 asm volatile("s_waitcnt vmcnt(4)" ::: "memory")
#define WAIT0 asm volatile("s_waitcnt vmcnt(0)" ::: "memory")

    ISSUE(0, b0);
    ISSUE(1, b1);
    for (int s = 0; s < 70; s += 2) {
        WAIT4; STEPX(s, b0, 1, s + 2);
        WAIT4; STEPX(s + 1, b1, 1, s + 3);
    }
    WAIT4; STEPX(70, b0, 0, 0);
    WAIT0; STEPX(71, b1, 0, 0);
#undef ISSUE
#undef STEPX
#undef WAIT4
#undef WAIT0

#pragma unroll
    for (int nt = 0; nt < 4; nt++) {
        int ch = wv * 64 + nt * 16 + lr;
        float bias = bconv[ch];
#pragma unroll
        for (int mt = 0; mt < 4; mt++) {
#pragma unroll
            for (int r = 0; r < 4; r++) {
                int p = mt * 16 + lg * 4 + r;
                if (p < 56) {
                    int ar = rbase + p / 7, c = p % 7;
                    int token = ar * WW + wi * WSP + c;
                    out[((size_t)b * NTOK + token) * CCH + ch] = acc[mt][nt][r] + bias;
                }
            }
        }
    }
}

// ---------------------------------------------------------------- attention
// One block per (win, head), 256 threads (4 waves), 4 blocks/CU target.
// Vs (V^T bf16) staged via 7 exact global_load_lds iterations from Vt.
// K fragments read DIRECTLY from global bf16 Kb (L2-resident, coalesced).
// Swapped QK^T (lane owns q-row), two macro-expanded key halves, online
// rescale; P transposed via per-wave LDS bounce.
// launch_bounds(256, 2): empirically cap = 256/arg on this toolchain
// ((512,4)->64, (512,2)->128, (256,4)->64) -> arg 2 gives the 128-reg cap
// this compute structure needs (R7: 128 regs, no spill, FETCH ~ideal).
// HW residency then = 512/128 = 4 waves/SIMD = 4 blocks/CU (LDS 33.3KB x4 ok).
__global__ __launch_bounds__(256, 2) void attn3(const float* __restrict__ qkv,
        const __bf16* __restrict__ Kb, const __bf16* __restrict__ Vt,
        float* __restrict__ out) {
    const int wh = blockIdx.x;
    const int win = wh >> 3, h = wh & 7;
    const int b = win >> 3, wi = win & 7;
    const int tid = threadIdx.x;
    const int lane = tid & 63, wv = tid >> 6;
    const int lr = lane & 15, lg = lane >> 4;
    const float scale = 0.17677669529663687f;   // 32^-0.5

    __shared__ __bf16 Vs[VT_STRIDE];            // 28,672 B ([32][424] used)
    __shared__ __bf16 Pb[4][16 * PB_S];         //  4,608 B  (total 33,280)

    const size_t plane = (size_t)NBATCH * NTOK * CCH;
    const float* qsrc = qkv + ((size_t)b * NTOK) * CCH + h * HDIM;
    const __bf16* kb = Kb + (size_t)wh * KB_STRIDE;
    const __bf16* vt = Vt + (size_t)wh * VT_STRIDE;

    // ---- stage Vs: 7 x (256 lanes x 16 B) = 28,672 B, linear copy
#pragma unroll
    for (int i = 0; i < 7; i++) {
        GLDS(vt + (i * 256 + tid) * 8, &Vs[(i * 256 + wv * 64) * 8]);
    }
    asm volatile("s_waitcnt vmcnt(0)" ::: "memory");
    __syncthreads();
#undef GLDS

    __bf16* pb = Pb[wv];
    for (int tile = wv; tile < 25; tile += 4) {
        // ---- Q fragment (B-operand) direct from f32, scaled
        int qrow = tile * 16 + lr;
        int qe = qrow < LTOK ? qrow : LTOK - 1;
        int tokq = (qe / 7) * WW + wi * WSP + qe % 7;
        const float* qp = qsrc + (size_t)tokq * CCH + lg * 8;
        f32x4 qa = *(const f32x4*)qp;
        f32x4 qc = *(const f32x4*)(qp + 4);
        bf16x8 aq;
#pragma unroll
        for (int i = 0; i < 4; i++) {
            aq[i] = (__bf16)(qa[i] * scale);
            aq[4 + i] = (__bf16)(qc[i] * scale);
        }

        float m_run = 0.f, sum_run = 0.f;
        f32x4 xacc[2] = {{0.f, 0.f, 0.f, 0.f}, {0.f, 0.f, 0.f, 0.f}};

#define HALF_PASS(NT, TB, NC, FIRST) do {                                   \
    f32x4 s[NT];                                                            \
    _Pragma("unroll")                                                       \
    for (int t = 0; t < NT; t++) {                                          \
        bf16x8 bk = *(const bf16x8*)(kb + ((TB + t) * 16 + lr) * 32 + lg * 8); \
        s[t] = __builtin_amdgcn_mfma_f32_16x16x32_bf16(                     \
            bk, aq, (f32x4){0.f, 0.f, 0.f, 0.f}, 0, 0, 0);                  \
    }                                                                       \
    f32x4 vm = s[0];                                                        \
    _Pragma("unroll")                                                       \
    for (int t = 1; t < 12; t++) {                                          \
        _Pragma("unroll")                                                   \
        for (int r = 0; r < 4; r++) vm[r] = fmaxf(vm[r], s[t][r]);          \
    }                                                                       \
    if (NT == 13 && lg < 2) {                                               \
        _Pragma("unroll")                                                   \
        for (int r = 0; r < 4; r++) vm[r] = fmaxf(vm[r], s[NT - 1][r]);     \
    }                                                                       \
    float mh = fmaxf(fmaxf(vm[0], vm[1]), fmaxf(vm[2], vm[3]));             \
    mh = fmaxf(mh, __shfl_xor(mh, 16, 64));                                 \
    mh = fmaxf(mh, __shfl_xor(mh, 32, 64));                                 \
    float m_new = FIRST ? mh : fmaxf(m_run, mh);                            \
    if (!FIRST) {                                                           \
        float f = __expf(m_run - m_new);                                    \
        sum_run *= f;                                                       \
        _Pragma("unroll")                                                   \
        for (int r = 0; r < 4; r++) {                                       \
            float fr = __shfl(f, 4 * lg + r, 64);                           \
            xacc[0][r] *= fr;                                               \
            xacc[1][r] *= fr;                                               \
        }                                                                   \
    }                                                                       \
    m_run = m_new;                                                          \
    f32x4 vsum = {0.f, 0.f, 0.f, 0.f};                                      \
    _Pragma("unroll")                                                       \
    for (int t = 0; t < 12; t++) {                                          \
        _Pragma("unroll")                                                   \
        for (int r = 0; r < 4; r++) {                                       \
            float e = __expf(s[t][r] - m_new);                              \
            s[t][r] = e;                                                    \
            vsum[r] += e;                                                   \
        }                                                                   \
    }                                                                       \
    if (NT == 13) {                                                         \
        if (lg < 2) {                                                       \
            _Pragma("unroll")                                               \
            for (int r = 0; r < 4; r++) {                                   \
                float e = __expf(s[NT - 1][r] - m_new);                     \
                s[NT - 1][r] = e;                                           \
                vsum[r] += e;                                               \
            }                                                               \
        } else {                                                            \
            _Pragma("unroll")                                               \
            for (int r = 0; r < 4; r++) s[NT - 1][r] = 0.f;                 \
        }                                                                   \
    }                                                                       \
    float sumh = (vsum[0] + vsum[1]) + (vsum[2] + vsum[3]);                 \
    sumh += __shfl_xor(sumh, 16, 64);                                       \
    sumh += __shfl_xor(sumh, 32, 64);                                       \
    sum_run += sumh;                                                        \
    _Pragma("unroll")                                                       \
    for (int c = 0; c < NC; c++) {                                          \
        uint2 wa, wb;                                                       \
        wa.x = pkbf(s[2 * c][0], s[2 * c][1]);                              \
        wa.y = pkbf(s[2 * c][2], s[2 * c][3]);                              \
        if (2 * c + 1 < NT) {                                               \
            wb.x = pkbf(s[2 * c + 1][0], s[2 * c + 1][1]);                  \
            wb.y = pkbf(s[2 * c + 1][2], s[2 * c + 1][3]);                  \
        } else {                                                            \
            wb.x = 0u; wb.y = 0u;                                           \
        }                                                                   \
        *(uint2*)&pb[lr * PB_S + 4 * lg] = wa;                              \
        *(uint2*)&pb[lr * PB_S + 16 + 4 * lg] = wb;                         \
        bf16x4 lo = *(const bf16x4*)&pb[lr * PB_S + 8 * lg];                \
        bf16x4 hi = *(const bf16x4*)&pb[lr * PB_S + 8 * lg + 4];            \
        bf16x8 ap;                                                          \
        _Pragma("unroll")                                                   \
        for (int i = 0; i < 4; i++) { ap[i] = lo[i]; ap[4 + i] = hi[i]; }   \
        const int kbase = TB * 16 + c * 32;                                 \
        _Pragma("unroll")                                                   \
        for (int nt = 0; nt < 2; nt++) {                                    \
            bf16x8 bv = *(const bf16x8*)&Vs[(nt * 16 + lr) * VT_ROW + kbase + lg * 8]; \
            xacc[nt] = __builtin_amdgcn_mfma_f32_16x16x32_bf16(             \
                ap, bv, xacc[nt], 0, 0, 0);                                 \
        }                                                                   \
    }                                                                       \
} while (0)

        HALF_PASS(12, 0, 6, 1);
        HALF_PASS(13, 12, 7, 0);
#undef HALF_PASS

        // ---- write out (RMW add onto conv output); rows q = tile*16+4lg+r
        float inv = 1.0f / sum_run;
#pragma unroll
        for (int r = 0; r < 4; r++) {
            float invr = __shfl(inv, 4 * lg + r, 64);
            int q = tile * 16 + 4 * lg + r;
            if (q < LTOK) {
                int rI = q / 7, c = q % 7;
                size_t base = ((size_t)b * NTOK + rI * WW + wi * WSP + c) * CCH + h * HDIM;
#pragma unroll
                for (int nt = 0; nt < 2; nt++)
                    out[base + nt * 16 + lr] += xacc[nt][r] * invr;
            }
        }
    }
}

// ---------------------------------------------------------------- launch
extern "C" void kernel_launch(void* const* d_in, const int* in_sizes, int n_in,
                              void* d_out, int out_size, void* d_ws, size_t ws_size,
                              hipStream_t stream) {
    const float* qkv = (const float*)d_in[0];
    const float* wconv = (const float*)d_in[1];
    const float* bconv = (const float*)d_in[2];
    float* out = (float*)d_out;
    char* ws = (char*)d_ws;

    const size_t KB_BYTES = (size_t)NWIN * NHEADS * KB_STRIDE * 2;   // 26,214,400
    const size_t VT_BYTES = (size_t)NWIN * NHEADS * VT_STRIDE * 2;   // 29,360,128
    const size_t WT_BYTES = (size_t)9 * CCH * CCH * 2;               //  1,179,648
    if (ws_size < KB_BYTES + VT_BYTES + WT_BYTES) return;

    __bf16* Kb = (__bf16*)ws;
    __bf16* Vt = (__bf16*)(ws + KB_BYTES);
    __bf16* Wt = (__bf16*)(ws + KB_BYTES + VT_BYTES);

    pack_kvw<<<NWIN * NHEADS, 256, 0, stream>>>(qkv, wconv, Kb, Vt, Wt);
    lepe_conv<<<NWIN * 7, 256, 0, stream>>>(qkv, Wt, bconv, out);
    attn3<<<NWIN * NHEADS, 256, 0, stream>>>(qkv, Kb, Vt, out);
}